// Round 6
// baseline (55.900 us; speedup 1.0000x reference)
//
#include <hip/hip_runtime.h>

// SIR RK4, B=65536, 200 points, out (B,200,3) f32 = 157.3 MB.
// Round 6: checkpoint split to raise wave count during the store-bound phase.
// Pass 1: 65536 threads integrate 180 steps, store states after steps
//   20,40,...,180 to d_ws (9 x B float4).
// Pass 2: 10 segment-threads per system (655360 threads, 10240 single-wave
//   blocks, ~40 queued blocks/CU) each produce 20 points from their
//   checkpoint, LDS-transpose, flush 15 coalesced float4 stores.
// Step sequence is bitwise identical to the single-kernel version.

#define SEG   20
#define NSEG  10
#define ROW_F 68     // 20 pts * 3 = 60 floats + 8 pad (17 float4 row stride)

__device__ __forceinline__ void rk4_step(float beta, float gamma,
                                         float& S, float& I, float& R)
{
    const float dt = 100.0f / 199.0f;
    const float h2 = 0.5f * dt;
    const float h6 = dt / 6.0f;
    float bSI1 = beta * S * I;
    float gI1  = gamma * I;
    float k1S = -bSI1, k1I = bSI1 - gI1, k1R = gI1;
    float S2 = __builtin_fmaf(h2, k1S, S);
    float I2 = __builtin_fmaf(h2, k1I, I);
    float bSI2 = beta * S2 * I2;
    float gI2  = gamma * I2;
    float k2S = -bSI2, k2I = bSI2 - gI2, k2R = gI2;
    float S3 = __builtin_fmaf(h2, k2S, S);
    float I3 = __builtin_fmaf(h2, k2I, I);
    float bSI3 = beta * S3 * I3;
    float gI3  = gamma * I3;
    float k3S = -bSI3, k3I = bSI3 - gI3, k3R = gI3;
    float S4 = __builtin_fmaf(dt, k3S, S);
    float I4 = __builtin_fmaf(dt, k3I, I);
    float bSI4 = beta * S4 * I4;
    float gI4  = gamma * I4;
    float k4S = -bSI4, k4I = bSI4 - gI4, k4R = gI4;
    S = __builtin_fmaf(h6, k1S + 2.0f * (k2S + k3S) + k4S, S);
    I = __builtin_fmaf(h6, k1I + 2.0f * (k2I + k3I) + k4I, I);
    R = __builtin_fmaf(h6, k1R + 2.0f * (k2R + k3R) + k4R, R);
}

__global__ __launch_bounds__(256) void sir_pass1(
    const float* __restrict__ params, float4* __restrict__ cp, int B)
{
    const int b = blockIdx.x * 256 + threadIdx.x;
    const float4 p = reinterpret_cast<const float4*>(params)[b];
    const float beta = p.x, gamma = p.y;
    float S = p.z, I = p.w;
    float R = 1.0f - S - I;
    #pragma unroll 1
    for (int k = 0; k < NSEG - 1; ++k) {
        #pragma unroll 4
        for (int j = 0; j < SEG; ++j) rk4_step(beta, gamma, S, I, R);
        cp[k * B + b] = make_float4(S, I, R, 0.0f);
    }
}

__global__ __launch_bounds__(64) void sir_pass2(
    const float* __restrict__ params, const float4* __restrict__ cp,
    float* __restrict__ out, int B)
{
    const int bid = blockIdx.x;
    const int s = bid % NSEG;          // segment 0..9
    const int i = bid / NSEG;          // system group (64 systems)
    const int t = threadIdx.x;
    const int b = i * 64 + t;

    __shared__ float lbuf[64 * ROW_F];

    const float4 p = reinterpret_cast<const float4*>(params)[b];
    const float beta = p.x, gamma = p.y;
    float S, I, R;
    if (s == 0) { S = p.z; I = p.w; R = 1.0f - S - I; }
    else        { float4 c = cp[(s - 1) * B + b]; S = c.x; I = c.y; R = c.z; }

    // integrate 20 points (point 0 = checkpoint state itself, then 19 steps)
    float4* lrow = reinterpret_cast<float4*>(&lbuf[t * ROW_F]);
    {
        float4 va, vb, vc;
        va.x = S; va.y = I; va.z = R;
        rk4_step(beta, gamma, S, I, R); va.w = S; vb.x = I; vb.y = R;
        rk4_step(beta, gamma, S, I, R); vb.z = S; vb.w = I; vc.x = R;
        rk4_step(beta, gamma, S, I, R); vc.y = S; vc.z = I; vc.w = R;
        lrow[0] = va; lrow[1] = vb; lrow[2] = vc;
        #pragma unroll
        for (int g = 1; g < 5; ++g) {
            rk4_step(beta, gamma, S, I, R); va.x = S; va.y = I; va.z = R;
            rk4_step(beta, gamma, S, I, R); va.w = S; vb.x = I; vb.y = R;
            rk4_step(beta, gamma, S, I, R); vb.z = S; vb.w = I; vc.x = R;
            rk4_step(beta, gamma, S, I, R); vc.y = S; vc.z = I; vc.w = R;
            lrow[g * 3 + 0] = va; lrow[g * 3 + 1] = vb; lrow[g * 3 + 2] = vc;
        }
    }

    // barrier-free coalesced flush: 64 rows x 15 float4 (240 B runs)
    float4* gout = reinterpret_cast<float4*>(out) + (size_t)i * 64 * 150 + s * 15;
    #pragma unroll 5
    for (int it = 0; it < 15; ++it) {
        int f = it * 64 + t;
        int r = f / 15;
        int q = f - r * 15;
        float4 v = *reinterpret_cast<const float4*>(&lbuf[r * ROW_F + q * 4]);
        gout[(size_t)r * 150 + q] = v;
    }
}

// Fallback (R3 kernel) if d_ws is too small for checkpoints.
#define FB_ROW_F  124
__global__ __launch_bounds__(64) void sir_fused(
    const float* __restrict__ params, float* __restrict__ out)
{
    const int t  = threadIdx.x;
    const int b0 = blockIdx.x * 64;
    __shared__ float lbuf[64 * FB_ROW_F];
    const float4 p = reinterpret_cast<const float4*>(params)[b0 + t];
    const float beta = p.x, gamma = p.y;
    float S = p.z, I = p.w;
    float R = 1.0f - S - I;
    float4* lrow = reinterpret_cast<float4*>(&lbuf[t * FB_ROW_F]);
    float4* gout = reinterpret_cast<float4*>(out) + (size_t)b0 * 150;
    for (int c = 0; c < 5; ++c) {
        #pragma unroll
        for (int g = 0; g < 10; ++g) {
            float4 va, vb, vc;
            if (c == 0 && g == 0) { va.x = S; va.y = I; va.z = R; }
            else { rk4_step(beta, gamma, S, I, R); va.x = S; va.y = I; va.z = R; }
            rk4_step(beta, gamma, S, I, R); va.w = S; vb.x = I; vb.y = R;
            rk4_step(beta, gamma, S, I, R); vb.z = S; vb.w = I; vc.x = R;
            rk4_step(beta, gamma, S, I, R); vc.y = S; vc.z = I; vc.w = R;
            lrow[g * 3 + 0] = va; lrow[g * 3 + 1] = vb; lrow[g * 3 + 2] = vc;
        }
        #pragma unroll 6
        for (int it = 0; it < 30; ++it) {
            int f = it * 64 + t;
            int r = f / 30;
            int q = f - r * 30;
            float4 v = *reinterpret_cast<const float4*>(&lbuf[r * FB_ROW_F + q * 4]);
            gout[(size_t)r * 150 + c * 30 + q] = v;
        }
    }
}

extern "C" void kernel_launch(void* const* d_in, const int* in_sizes, int n_in,
                              void* d_out, int out_size, void* d_ws, size_t ws_size,
                              hipStream_t stream) {
    const float* params = (const float*)d_in[0];
    float* out = (float*)d_out;
    const int B = in_sizes[0] / 4;                       // 65536
    const size_t cp_bytes = (size_t)(NSEG - 1) * B * 16; // 9.4 MB
    if (ws_size >= cp_bytes) {
        float4* cp = (float4*)d_ws;
        sir_pass1<<<B / 256, 256, 0, stream>>>(params, cp, B);
        sir_pass2<<<(B / 64) * NSEG, 64, 0, stream>>>(params, cp, out, B);
    } else {
        sir_fused<<<B / 64, 64, 0, stream>>>(params, out);
    }
}